// Round 1
// baseline (490.103 us; speedup 1.0000x reference)
//
#include <hip/hip_runtime.h>

#define HH 128
#define WW 128
#define CIN 128
#define COUT 256
#define BATCH 2
#define K9 9
#define HW (HH*WW)          // 16384
#define PIX (BATCH*HW)      // 32768
#define KDIM (CIN*K9)       // 1152
#define BN_EPS 1e-5f

struct Meta { int4 idx; float4 w; };   // 32B: 4 clamped hw-indices + 4 premultiplied weights

// ---------------------------------------------------------------------------
// Kernel A: per (pixel, k) compute dy (ch 2k), dx (ch 2k+1), mask (ch 18+k)
// of the 3x3 SAME conv, then bilinear sampling metadata.
// grid = (PIX/256, 9), block = 256. blockIdx.y = k -> weight addrs wave-uniform.
// ---------------------------------------------------------------------------
__global__ __launch_bounds__(256) void offs_kernel(
    const float* __restrict__ x, const float* __restrict__ w_off,
    const float* __restrict__ b_off, Meta* __restrict__ meta)
{
    const int pg = blockIdx.x * 256 + threadIdx.x;   // global pixel
    const int k  = blockIdx.y;
    const int b  = pg >> 14;
    const int hw = pg & 16383;
    const int h  = hw >> 7;
    const int w  = hw & 127;

    const float* __restrict__ wdy = w_off + (2*k)   * KDIM;
    const float* __restrict__ wdx = w_off + (2*k+1) * KDIM;
    const float* __restrict__ wm  = w_off + (18+k)  * KDIM;

    float dy = b_off[2*k], dx = b_off[2*k+1], mm = b_off[18+k];

    const float* __restrict__ xb = x + (size_t)b * (CIN*HW);
    for (int c = 0; c < CIN; ++c) {
        const float* __restrict__ xc = xb + c * HW;
        const int wbase = c * 9;
        #pragma unroll
        for (int kh = 0; kh < 3; ++kh) {
            const int yy = h + kh - 1;
            const bool yok = ((unsigned)yy < HH);
            const int rowoff = yy * WW;
            #pragma unroll
            for (int kw = 0; kw < 3; ++kw) {
                const int xx = w + kw - 1;
                float v = (yok && ((unsigned)xx < WW)) ? xc[rowoff + xx] : 0.f;
                const int wi = wbase + kh*3 + kw;
                dy = fmaf(v, wdy[wi], dy);
                dx = fmaf(v, wdx[wi], dx);
                mm = fmaf(v, wm[wi],  mm);
            }
        }
    }

    // sampling position
    const float ky = (float)(k / 3) - 1.0f;
    const float kx = (float)(k % 3) - 1.0f;
    const float py = (float)h + ky + dy;
    const float px = (float)w + kx + dx;
    const float msk = 1.0f / (1.0f + expf(-mm));

    const float y0f = floorf(py);
    const float x0f = floorf(px);
    const float wy = py - y0f;
    const float wx = px - x0f;
    const int y0 = (int)y0f, x0 = (int)x0f;
    const int y1 = y0 + 1,   x1 = x0 + 1;

    const bool v00 = ((unsigned)y0 < HH) && ((unsigned)x0 < WW);
    const bool v01 = ((unsigned)y0 < HH) && ((unsigned)x1 < WW);
    const bool v10 = ((unsigned)y1 < HH) && ((unsigned)x0 < WW);
    const bool v11 = ((unsigned)y1 < HH) && ((unsigned)x1 < WW);

    const int y0c = min(max(y0, 0), HH-1), y1c = min(max(y1, 0), HH-1);
    const int x0c = min(max(x0, 0), WW-1), x1c = min(max(x1, 0), WW-1);

    Meta m;
    m.idx.x = y0c * WW + x0c;
    m.idx.y = y0c * WW + x1c;
    m.idx.z = y1c * WW + x0c;
    m.idx.w = y1c * WW + x1c;
    m.w.x = v00 ? (1.f-wy)*(1.f-wx)*msk : 0.f;
    m.w.y = v01 ? (1.f-wy)*wx*msk       : 0.f;
    m.w.z = v10 ? wy*(1.f-wx)*msk       : 0.f;
    m.w.w = v11 ? wy*wx*msk             : 0.f;
    meta[pg * K9 + k] = m;
}

// ---------------------------------------------------------------------------
// Kernel B: implicit GEMM  out[p][o] = sum_e val[p][e] * w_dcn[o][e],
// e = c*9+k, val gathered via meta. 64 pixels x 256 outputs per block,
// BK=32, 512 threads (8 waves). Fused BN+ReLU epilogue.
// ---------------------------------------------------------------------------
__global__ __launch_bounds__(512) void dcn_kernel(
    const float* __restrict__ x, const Meta* __restrict__ meta,
    const float* __restrict__ w_dcn, const float* __restrict__ b_dcn,
    const float* __restrict__ gamma, const float* __restrict__ beta,
    const float* __restrict__ mmean, const float* __restrict__ mvar,
    float* __restrict__ out)
{
    __shared__ float As[64][32];    // [pixel][ee]
    __shared__ float Bs[32][256];   // [ee][o]

    const int t   = threadIdx.x;
    const int pg0 = blockIdx.x * 64;          // 64 pixels, all in same batch b
    const int b   = pg0 >> 14;
    const int hw0 = pg0 & 16383;
    const float* __restrict__ xb = x + (size_t)b * (CIN*HW);

    const int ot = t & 63;    // o lane: o = ot + 64*jj
    const int pt = t >> 6;    // pixel group: p = pt + 8*pp

    float acc[8][4];
    #pragma unroll
    for (int pp = 0; pp < 8; ++pp)
        #pragma unroll
        for (int jj = 0; jj < 4; ++jj) acc[pp][jj] = 0.f;

    for (int e0 = 0; e0 < KDIM; e0 += 32) {
        __syncthreads();
        // --- stage A: 64px * 32e = 2048 gathered values ---
        #pragma unroll
        for (int r = 0; r < 4; ++r) {
            const int l  = t + r * 512;
            const int p  = l >> 5;
            const int ee = l & 31;
            const int e  = e0 + ee;
            const int c  = e / 9;
            const int k  = e - c * 9;
            const Meta m = meta[(pg0 + p) * K9 + k];
            const float* __restrict__ xc = xb + c * HW;
            const float v = m.w.x * xc[m.idx.x] + m.w.y * xc[m.idx.y]
                          + m.w.z * xc[m.idx.z] + m.w.w * xc[m.idx.w];
            As[p][ee] = v;
        }
        // --- stage B: Bs[ee][o] = w_dcn[o*KDIM + e0+ee] (transpose on load) ---
        {
            const int o  = t & 255;
            const int eh = (t >> 8) * 16;  // 0 or 16
            const float4* __restrict__ wp =
                (const float4*)(w_dcn + (size_t)o * KDIM + e0 + eh);
            #pragma unroll
            for (int q = 0; q < 4; ++q) {
                const float4 wv = wp[q];
                Bs[eh + q*4 + 0][o] = wv.x;
                Bs[eh + q*4 + 1][o] = wv.y;
                Bs[eh + q*4 + 2][o] = wv.z;
                Bs[eh + q*4 + 3][o] = wv.w;
            }
        }
        __syncthreads();
        // --- compute: 32 ee, 8px x 4o register tile ---
        #pragma unroll
        for (int ee = 0; ee < 32; ++ee) {
            float bv[4], av[8];
            #pragma unroll
            for (int jj = 0; jj < 4; ++jj) bv[jj] = Bs[ee][ot + 64*jj];
            #pragma unroll
            for (int pp = 0; pp < 8; ++pp) av[pp] = As[pt + 8*pp][ee];
            #pragma unroll
            for (int pp = 0; pp < 8; ++pp)
                #pragma unroll
                for (int jj = 0; jj < 4; ++jj)
                    acc[pp][jj] = fmaf(av[pp], bv[jj], acc[pp][jj]);
        }
    }

    // --- epilogue: bias + BN + ReLU, store ---
    #pragma unroll
    for (int jj = 0; jj < 4; ++jj) {
        const int o = ot + 64*jj;
        const float sc = gamma[o] * rsqrtf(mvar[o] + BN_EPS);
        const float sh = (b_dcn[o] - mmean[o]) * sc + beta[o];
        float* __restrict__ op = out + ((size_t)(b * COUT + o) << 14) + hw0;
        #pragma unroll
        for (int pp = 0; pp < 8; ++pp) {
            const float v = fmaf(acc[pp][jj], sc, sh);
            op[pt + 8*pp] = fmaxf(v, 0.f);
        }
    }
}

extern "C" void kernel_launch(void* const* d_in, const int* in_sizes, int n_in,
                              void* d_out, int out_size, void* d_ws, size_t ws_size,
                              hipStream_t stream) {
    (void)in_sizes; (void)n_in; (void)out_size; (void)ws_size;
    const float* x      = (const float*)d_in[0];
    const float* w_off  = (const float*)d_in[1];
    const float* b_off  = (const float*)d_in[2];
    const float* w_dcn  = (const float*)d_in[3];
    const float* b_dcn  = (const float*)d_in[4];
    const float* gamma  = (const float*)d_in[5];
    const float* beta   = (const float*)d_in[6];
    const float* mmean  = (const float*)d_in[7];
    const float* mvar   = (const float*)d_in[8];
    float* out = (float*)d_out;
    Meta* meta = (Meta*)d_ws;   // PIX*K9*32B = 9.4 MB

    offs_kernel<<<dim3(PIX/256, K9), 256, 0, stream>>>(x, w_off, b_off, meta);
    dcn_kernel<<<dim3(PIX/64), 512, 0, stream>>>(x, meta, w_dcn, b_dcn,
                                                 gamma, beta, mmean, mvar, out);
}

// Round 2
// 219.499 us; speedup vs baseline: 2.2328x; 2.2328x over previous
//
#include <hip/hip_runtime.h>
#include <hip/hip_fp16.h>

#define HH 128
#define WW 128
#define CIN 128
#define COUT 256
#define K9 9
#define HW (HH*WW)          // 16384
#define PIX (2*HW)          // 32768
#define KDIM (CIN*K9)       // 1152
#define BN_EPS 1e-5f

typedef __attribute__((ext_vector_type(8))) short short8;
typedef __attribute__((ext_vector_type(4))) float f32x4;

// 16B sampling metadata: 4 clamped hw-indices (u16) + 4 premultiplied bilinear
// weights (f16, mask & validity folded in).
struct Meta16 { ushort4 idx; __half2 w01, w23; };
static_assert(sizeof(Meta16) == 16, "");

__device__ __forceinline__ unsigned short f2bf(float f) {
    union { float f; unsigned u; } x; x.f = f;
    unsigned r = x.u + 0x7FFFu + ((x.u >> 16) & 1u);
    return (unsigned short)(r >> 16);
}

// ---------------------------------------------------------------------------
// prep_w: wT[o][e'] = bf16(w_dcn[o][c][k]), e' = k*128 + c  (k-major K order)
// ---------------------------------------------------------------------------
__global__ __launch_bounds__(128) void prep_w(const float* __restrict__ w_dcn,
                                              unsigned short* __restrict__ wT) {
    const int c = threadIdx.x;     // 0..127
    const int k = blockIdx.x;      // 0..8
    const int o = blockIdx.y;      // 0..255
    wT[(size_t)o*KDIM + k*CIN + c] = f2bf(w_dcn[(size_t)o*KDIM + c*K9 + k]);
}

// ---------------------------------------------------------------------------
// offs_kernel: per (pixel, k) compute dy (ch 2k), dx (ch 2k+1), mask (ch 18+k)
// of the 3x3 SAME conv, then write compressed bilinear metadata.
// ---------------------------------------------------------------------------
__global__ __launch_bounds__(256) void offs_kernel(
    const float* __restrict__ x, const float* __restrict__ w_off,
    const float* __restrict__ b_off, Meta16* __restrict__ meta)
{
    const int pg = blockIdx.x * 256 + threadIdx.x;
    const int k  = blockIdx.y;
    const int b  = pg >> 14;
    const int hw = pg & 16383;
    const int h  = hw >> 7;
    const int w  = hw & 127;

    const float* __restrict__ wdy = w_off + (2*k)   * KDIM;
    const float* __restrict__ wdx = w_off + (2*k+1) * KDIM;
    const float* __restrict__ wm  = w_off + (18+k)  * KDIM;

    float dy = b_off[2*k], dx = b_off[2*k+1], mm = b_off[18+k];

    const float* __restrict__ xb = x + (size_t)b * (CIN*HW);
    for (int c = 0; c < CIN; ++c) {
        const float* __restrict__ xc = xb + c * HW;
        const int wbase = c * 9;
        #pragma unroll
        for (int kh = 0; kh < 3; ++kh) {
            const int yy = h + kh - 1;
            const bool yok = ((unsigned)yy < HH);
            const int rowoff = yy * WW;
            #pragma unroll
            for (int kw = 0; kw < 3; ++kw) {
                const int xx = w + kw - 1;
                float v = (yok && ((unsigned)xx < WW)) ? xc[rowoff + xx] : 0.f;
                const int wi = wbase + kh*3 + kw;
                dy = fmaf(v, wdy[wi], dy);
                dx = fmaf(v, wdx[wi], dx);
                mm = fmaf(v, wm[wi],  mm);
            }
        }
    }

    const float ky = (float)(k / 3) - 1.0f;
    const float kx = (float)(k % 3) - 1.0f;
    const float py = (float)h + ky + dy;
    const float px = (float)w + kx + dx;
    const float msk = 1.0f / (1.0f + expf(-mm));

    const float y0f = floorf(py);
    const float x0f = floorf(px);
    const float wy = py - y0f;
    const float wx = px - x0f;
    const int y0 = (int)y0f, x0 = (int)x0f;
    const int y1 = y0 + 1,   x1 = x0 + 1;

    const bool v00 = ((unsigned)y0 < HH) && ((unsigned)x0 < WW);
    const bool v01 = ((unsigned)y0 < HH) && ((unsigned)x1 < WW);
    const bool v10 = ((unsigned)y1 < HH) && ((unsigned)x0 < WW);
    const bool v11 = ((unsigned)y1 < HH) && ((unsigned)x1 < WW);

    const int y0c = min(max(y0, 0), HH-1), y1c = min(max(y1, 0), HH-1);
    const int x0c = min(max(x0, 0), WW-1), x1c = min(max(x1, 0), WW-1);

    Meta16 m;
    m.idx.x = (unsigned short)(y0c * WW + x0c);
    m.idx.y = (unsigned short)(y0c * WW + x1c);
    m.idx.z = (unsigned short)(y1c * WW + x0c);
    m.idx.w = (unsigned short)(y1c * WW + x1c);
    const float f00 = v00 ? (1.f-wy)*(1.f-wx)*msk : 0.f;
    const float f01 = v01 ? (1.f-wy)*wx*msk       : 0.f;
    const float f10 = v10 ? wy*(1.f-wx)*msk       : 0.f;
    const float f11 = v11 ? wy*wx*msk             : 0.f;
    m.w01 = __floats2half2_rn(f00, f01);
    m.w23 = __floats2half2_rn(f10, f11);
    meta[(size_t)pg * K9 + k] = m;
}

// ---------------------------------------------------------------------------
// dcn_mfma: implicit GEMM via mfma_f32_16x16x32_bf16.
//   M-side = 256 outputs (A-operand = wT, read from global/L2),
//   N-side = 64 pixels  (B-operand = gathered vals, staged bf16 in LDS),
//   K      = 1152 in e' = k*128+c order -> each BK=32 tile has ONE deform tap.
// 256 threads = 4 waves; wave w owns o in [64w, 64w+64). Fused BN+ReLU.
// ---------------------------------------------------------------------------
__global__ __launch_bounds__(256) void dcn_mfma(
    const float* __restrict__ x, const Meta16* __restrict__ meta,
    const unsigned short* __restrict__ wT,
    const float* __restrict__ b_dcn, const float* __restrict__ gamma,
    const float* __restrict__ beta, const float* __restrict__ mmean,
    const float* __restrict__ mvar, float* __restrict__ out)
{
    __shared__ __align__(16) unsigned short Vs[64*40];   // [p][kk], stride 40

    const int t   = threadIdx.x;
    const int l   = t & 63;
    const int wv  = t >> 6;        // wave 0..3 -> o block
    const int l15 = l & 15;
    const int lq  = l >> 4;

    const int pg0 = blockIdx.x * 64;
    const int b   = pg0 >> 14;
    const int hw0 = pg0 & 16383;
    const float* __restrict__ xb = x + (size_t)b * (CIN*HW);

    f32x4 acc[4][4];
    #pragma unroll
    for (int m = 0; m < 4; ++m)
        #pragma unroll
        for (int n = 0; n < 4; ++n) acc[m][n] = (f32x4){0.f,0.f,0.f,0.f};

    const int p   = l;     // gather: lane = pixel (coalesced-ish x reads)
    const int ee8 = wv;    // gather: wave = which 8-c octet

    for (int tt = 0; tt < 36; ++tt) {
        const int k  = tt >> 2;
        const int c0 = (tt & 3) * 32;

        __syncthreads();   // prev-tile B-frag reads done before Vs overwrite

        // A-frags (weights) straight from global (L2-resident, dense lines)
        short8 a[4];
        #pragma unroll
        for (int m = 0; m < 4; ++m) {
            const int o = wv*64 + m*16 + l15;
            a[m] = *(const short8*)(wT + (size_t)o*KDIM + tt*32 + lq*8);
        }

        // gather 8 vals (one meta, 8 consecutive c) -> bf16 -> LDS
        {
            const Meta16 mt = meta[(size_t)(pg0 + p) * K9 + k];
            const float w0 = __low2float(mt.w01), w1 = __high2float(mt.w01);
            const float w2 = __low2float(mt.w23), w3 = __high2float(mt.w23);
            const int i0 = mt.idx.x, i1 = mt.idx.y, i2 = mt.idx.z, i3 = mt.idx.w;
            short8 pk;
            #pragma unroll
            for (int j = 0; j < 8; ++j) {
                const float* __restrict__ xc = xb + (size_t)(c0 + ee8*8 + j) * HW;
                const float v = w0*xc[i0] + w1*xc[i1] + w2*xc[i2] + w3*xc[i3];
                pk[j] = (short)f2bf(v);
            }
            *(short8*)&Vs[p*40 + ee8*8] = pk;
        }

        __syncthreads();

        // B-frags from LDS + 16 MFMA
        #pragma unroll
        for (int n = 0; n < 4; ++n) {
            const short8 bf = *(const short8*)&Vs[(n*16 + l15)*40 + lq*8];
            #pragma unroll
            for (int m = 0; m < 4; ++m)
                acc[m][n] = __builtin_amdgcn_mfma_f32_16x16x32_bf16(
                                a[m], bf, acc[m][n], 0, 0, 0);
        }
    }

    // epilogue: BN + ReLU, coalesced stores (16 consecutive pixels / 16 lanes)
    #pragma unroll
    for (int m = 0; m < 4; ++m) {
        #pragma unroll
        for (int r = 0; r < 4; ++r) {
            const int o = wv*64 + m*16 + lq*4 + r;
            const float sc = gamma[o] * rsqrtf(mvar[o] + BN_EPS);
            const float sh = (b_dcn[o] - mmean[o]) * sc + beta[o];
            float* __restrict__ op = out + ((size_t)(b*COUT + o) << 14) + hw0;
            #pragma unroll
            for (int n = 0; n < 4; ++n) {
                const float v = fmaf(acc[m][n][r], sc, sh);
                op[n*16 + l15] = fmaxf(v, 0.f);
            }
        }
    }
}

extern "C" void kernel_launch(void* const* d_in, const int* in_sizes, int n_in,
                              void* d_out, int out_size, void* d_ws, size_t ws_size,
                              hipStream_t stream) {
    (void)in_sizes; (void)n_in; (void)out_size; (void)ws_size;
    const float* x      = (const float*)d_in[0];
    const float* w_off  = (const float*)d_in[1];
    const float* b_off  = (const float*)d_in[2];
    const float* w_dcn  = (const float*)d_in[3];
    const float* b_dcn  = (const float*)d_in[4];
    const float* gamma  = (const float*)d_in[5];
    const float* beta   = (const float*)d_in[6];
    const float* mmean  = (const float*)d_in[7];
    const float* mvar   = (const float*)d_in[8];
    float* out = (float*)d_out;

    unsigned short* wT = (unsigned short*)d_ws;                 // 589824 B
    Meta16* meta = (Meta16*)((char*)d_ws + (size_t)COUT*KDIM*2); // 4.72 MB

    prep_w<<<dim3(9, 256), 128, 0, stream>>>(w_dcn, wT);
    offs_kernel<<<dim3(PIX/256, K9), 256, 0, stream>>>(x, w_off, b_off, meta);
    dcn_mfma<<<dim3(PIX/64), 256, 0, stream>>>(x, meta, wT, b_dcn,
                                               gamma, beta, mmean, mvar, out);
}